// Round 11
// baseline (346.058 us; speedup 1.0000x reference)
//
#include <hip/hip_runtime.h>
#include <hip/hip_bf16.h>

#define NN 400
#define KMAX 64

struct WTab {
  const void* p[34];
  int off[35];
};

__device__ __forceinline__ float bflo(unsigned u) {
  union { unsigned i; float f; } x; x.i = u << 16; return x.f;
}
__device__ __forceinline__ float bfhi(unsigned u) {
  union { unsigned i; float f; } x; x.i = u & 0xffff0000u; return x.f;
}
__device__ __forceinline__ unsigned short f2bf(float f) {
  __hip_bfloat16 b = __float2bfloat16(f);
  return *reinterpret_cast<unsigned short*>(&b);
}
__device__ __forceinline__ unsigned packbf(float a, float b) {
  return (unsigned)f2bf(a) | ((unsigned)f2bf(b) << 16);
}
// Per-wave dtype sniff: bf16 data has plausible N(0,1) exponents at even u16s.
__device__ __forceinline__ bool detect_bf16(const unsigned short* probe) {
  int lane = threadIdx.x & 63;
  unsigned short u = probe[lane * 2];
  int e = (u >> 7) & 0xFF;
  bool plaus = (u == 0) || (e >= 112 && e <= 132);
  return __popcll(__ballot(plaus)) >= 48;
}
__device__ __forceinline__ float rsum32(float v) {
  v += __shfl_xor(v, 1); v += __shfl_xor(v, 2); v += __shfl_xor(v, 4);
  v += __shfl_xor(v, 8); v += __shfl_xor(v, 16); return v;
}

// ---------------------------------------------------------------------------
// prep: blocks 0..39 convert the 34 weight tensors (19905 elems) to fp32;
// blocks 40..139 build CSR (4 adjacency rows per block, one per wave).
// ---------------------------------------------------------------------------
__global__ __launch_bounds__(256) void prep_k(
    WTab wt, const void* __restrict__ adj,
    const unsigned short* __restrict__ probe, float* __restrict__ dst,
    int* __restrict__ colp, int* __restrict__ degp) {
  bool isbf = detect_bf16(probe);
  const int tid = threadIdx.x;
  if (blockIdx.x < 40) {
    int total = wt.off[34];
    for (int i = blockIdx.x * 256 + tid; i < total; i += 40 * 256) {
      int lo = 0, hi = 33;
      while (lo < hi) {
        int mid = (lo + hi + 1) >> 1;
        if (i >= wt.off[mid]) lo = mid; else hi = mid - 1;
      }
      int rel = i - wt.off[lo];
      float v;
      if (isbf) v = __bfloat162float(((const __hip_bfloat16*)wt.p[lo])[rel]);
      else      v = ((const float*)wt.p[lo])[rel];
      dst[i] = v;
    }
  } else {
    int row = (blockIdx.x - 40) * 4 + (tid >> 6);
    int lane = tid & 63;
    int base = 0;
    for (int j0 = 0; j0 < NN; j0 += 64) {
      int j = j0 + lane;
      bool nz;
      if (isbf) nz = (j < NN) && ((const unsigned short*)adj)[row * NN + j] != 0;
      else      nz = (j < NN) && ((const float*)adj)[row * NN + j] != 0.0f;
      unsigned long long m = __ballot(nz);
      int offl = __popcll(m & ((1ull << lane) - 1ull));
      if (nz) {
        int pidx = base + offl;
        if (pidx < KMAX) colp[row * KMAX + pidx] = j;
      }
      base += __popcll(m);
    }
    if (lane == 0) degp[row] = base < KMAX ? base : KMAX;
  }
}

// ---------------------------------------------------------------------------
// GAT1, all 4 heads, grid (192 graphs, 2 node-halves). Algebraic collapse:
//   s_ij = x_i·(M_h x_j) + c_i + d_j + s0,  M_h = Wq_h Wk_h^T (3x3)
//   o_i  = ((Σ_j p_ij x_j)/l) @ Wv_h + bv_h
// ---------------------------------------------------------------------------
__global__ __launch_bounds__(256) void gat1_k(
    const void* __restrict__ xraw, const unsigned short* __restrict__ probe,
    const float* __restrict__ g1, const int* __restrict__ colp,
    const int* __restrict__ degp, unsigned short* __restrict__ h1b) {
  __shared__ float xsf[NN * 4];
  __shared__ float yhf[4 * NN * 4];
  __shared__ float w1s[768];
  __shared__ float cf[64];
  const int tid = threadIdx.x;
  const int g = blockIdx.x;
  bool isbf = detect_bf16(probe);

  for (int e = tid; e < 768; e += 256) w1s[e] = g1[e];
  for (int e = tid; e < NN; e += 256) xsf[e * 4 + 3] = 0.f;
  for (int e = tid; e < NN * 3; e += 256) {
    int j = e / 3, a = e - j * 3;
    float v;
    if (isbf) v = __bfloat162float(((const __hip_bfloat16*)xraw)[g * NN * 3 + e]);
    else      v = ((const float*)xraw)[g * NN * 3 + e];
    xsf[j * 4 + a] = v;
  }
  __syncthreads();

  if (tid < 64) {
    int h = tid >> 4, t = tid & 15, co = h * 16;
    float acc = 0.f;
    if (t < 9) {
      int a = t / 3, b = t - (t / 3) * 3;
      for (int c = 0; c < 16; ++c) acc += w1s[a * 64 + co + c] * w1s[256 + b * 64 + co + c];
    } else if (t < 12) {
      int a = t - 9;
      for (int c = 0; c < 16; ++c) acc += w1s[a * 64 + co + c] * w1s[448 + co + c];
    } else if (t < 15) {
      int b = t - 12;
      for (int c = 0; c < 16; ++c) acc += w1s[256 + b * 64 + co + c] * w1s[192 + co + c];
    } else {
      for (int c = 0; c < 16; ++c) acc += w1s[192 + co + c] * w1s[448 + co + c];
    }
    cf[h * 16 + t] = acc;
  }
  __syncthreads();

  for (int e = tid; e < NN * 4; e += 256) {
    int j = e >> 2, h = e & 3;
    const float* bse = cf + h * 16;
    float x0 = xsf[j * 4], x1 = xsf[j * 4 + 1], x2 = xsf[j * 4 + 2];
    float* y = yhf + (h * NN + j) * 4;
    y[0] = bse[0] * x0 + bse[1] * x1 + bse[2] * x2;
    y[1] = bse[3] * x0 + bse[4] * x1 + bse[5] * x2;
    y[2] = bse[6] * x0 + bse[7] * x1 + bse[8] * x2;
    y[3] = bse[12] * x0 + bse[13] * x1 + bse[14] * x2 + bse[15];
  }
  __syncthreads();

  const float4* xs4 = (const float4*)xsf;
  const float4* yh4 = (const float4*)yhf;
  const int i0 = blockIdx.y * 200;
  for (int i = i0 + tid; i < i0 + 200; i += 256) {
    float4 xi = xs4[i];
    float ch[4];
    #pragma unroll
    for (int h = 0; h < 4; ++h)
      ch[h] = cf[h * 16 + 9] * xi.x + cf[h * 16 + 10] * xi.y + cf[h * 16 + 11] * xi.z;
    float l[4] = {0.f, 0.f, 0.f, 0.f};
    float ax[4], ay[4], az[4];
    #pragma unroll
    for (int h = 0; h < 4; ++h) { ax[h] = 0.f; ay[h] = 0.f; az[h] = 0.f; }
    int dg = degp[i];
    const int* cols = colp + i * KMAX;
    for (int e = 0; e < dg; ++e) {
      int j = cols[e];
      float4 xj = xs4[j];
      #pragma unroll
      for (int h = 0; h < 4; ++h) {
        float4 y = yh4[h * NN + j];
        float s = (xi.x * y.x + xi.y * y.y + xi.z * y.z + y.w + ch[h]) * 0.25f;
        float p = __expf(s);
        l[h] += p;
        ax[h] += p * xj.x; ay[h] += p * xj.y; az[h] += p * xj.z;
      }
    }
    unsigned* hr = (unsigned*)(h1b + ((size_t)g * NN + i) * 64);
    #pragma unroll
    for (int h = 0; h < 4; ++h) {
      float inv = 1.f / l[h];
      float b0 = ax[h] * inv, b1 = ay[h] * inv, b2 = az[h] * inv;
      int co = h * 16;
      #pragma unroll
      for (int c = 0; c < 16; c += 2) {
        float o0 = fmaxf(b0 * w1s[512 + co + c] + b1 * w1s[576 + co + c] +
                         b2 * w1s[640 + co + c] + w1s[704 + co + c], 0.f);
        float o1 = fmaxf(b0 * w1s[513 + co + c] + b1 * w1s[577 + co + c] +
                         b2 * w1s[641 + co + c] + w1s[705 + co + c], 0.f);
        hr[(co + c) >> 1] = packbf(o0, o1);
      }
    }
  }
}

// ---------------------------------------------------------------------------
// FUSED GAT2 proj + attention: one block per graph. Chunks of 64 nodes:
// stage h1b chunk transposed -> ht bf16 [64 d][72] (144B rows, uint4-aligned);
// proj chunk with gat2_proj's thread mapping (c=tid&31, ng=tid>>5, 8 nodes),
// k/v -> LDS bf16 stride-34 u16 (odd-dword bank spread), q -> global bf16.
// Then attention + residual + LN in the same kernel (no staging, no k/v
// global round-trip). LDS: 9216+27200+27200+256 = 63872 B.
// ---------------------------------------------------------------------------
__global__ __launch_bounds__(256) void projattn_k(
    const void* __restrict__ xraw, const unsigned short* __restrict__ probe,
    const unsigned short* __restrict__ h1b, const float* __restrict__ g2,
    const float* __restrict__ spw, const int* __restrict__ colp,
    const int* __restrict__ degp, unsigned short* __restrict__ q2b,
    float* __restrict__ spo) {
  __shared__ __align__(16) unsigned short ht[64 * 72];
  __shared__ unsigned short k2s[NN * 34];
  __shared__ unsigned short v2s[NN * 34];
  __shared__ float gw[64];
  const int tid = threadIdx.x;
  const int g = blockIdx.x;
  bool isbf = detect_bf16(probe);
  if (tid < 64) gw[tid] = spw[tid];

  // ---- proj phase: 7 chunks of <=64 nodes ----
  for (int c0 = 0; c0 < NN; c0 += 64) {
    const int rem = (NN - c0) < 64 ? (NN - c0) : 64;
    for (int e = tid; e < rem * 32; e += 256) {
      int ln = e >> 5, dp = e & 31;
      unsigned u = ((const unsigned*)h1b)[((size_t)g * NN + c0 + ln) * 32 + dp];
      ht[(2 * dp) * 72 + ln]     = (unsigned short)(u & 0xffffu);
      ht[(2 * dp + 1) * 72 + ln] = (unsigned short)(u >> 16);
    }
    __syncthreads();
    const int c = tid & 31, ng = tid >> 5;
    const int nbase = ng * 8;
    if (nbase < rem) {
      const float* wq = g2;
      const float* wk = g2 + 2080;
      const float* wv = g2 + 4160;
      float qa[8], ka[8], va[8];
      float bq = g2[2048 + c], bk = g2[4128 + c], bv = g2[6208 + c];
      #pragma unroll
      for (int k = 0; k < 8; ++k) { qa[k] = bq; ka[k] = bk; va[k] = bv; }
      for (int d = 0; d < 64; ++d) {
        float wqv = wq[d * 32 + c], wkv = wk[d * 32 + c], wvv = wv[d * 32 + c];
        uint4 hv4 = *(const uint4*)(ht + d * 72 + nbase);
        unsigned uu[4] = {hv4.x, hv4.y, hv4.z, hv4.w};
        #pragma unroll
        for (int m = 0; m < 4; ++m) {
          float h0 = bflo(uu[m]), h1v = bfhi(uu[m]);
          qa[2*m] += h0 * wqv;   qa[2*m+1] += h1v * wqv;
          ka[2*m] += h0 * wkv;   ka[2*m+1] += h1v * wkv;
          va[2*m] += h0 * wvv;   va[2*m+1] += h1v * wvv;
        }
      }
      #pragma unroll
      for (int k = 0; k < 8; ++k) {
        int n = c0 + nbase + k;
        q2b[((size_t)g * NN + n) * 32 + c] = f2bf(qa[k]);
        k2s[n * 34 + c] = f2bf(ka[k]);
        v2s[n * 34 + c] = f2bf(va[k]);
      }
    }
    __syncthreads();
  }

  // ---- attention + residual + LN phase ----
  const int b = g / 24, st = g % 24;
  for (int i = tid; i < NN; i += 256) {
    const uint4* qp = (const uint4*)(q2b + ((size_t)g * NN + i) * 32);
    uint4 qw[4] = {qp[0], qp[1], qp[2], qp[3]};
    float q[32], o[32];
    #pragma unroll
    for (int t = 0; t < 4; ++t) {
      unsigned uu[4] = {qw[t].x, qw[t].y, qw[t].z, qw[t].w};
      #pragma unroll
      for (int m = 0; m < 4; ++m) {
        q[t * 8 + 2 * m] = bflo(uu[m]); q[t * 8 + 2 * m + 1] = bfhi(uu[m]);
      }
    }
    #pragma unroll
    for (int c = 0; c < 32; ++c) o[c] = 0.f;
    int dg = degp[i];
    const int* cols = colp + i * KMAX;
    float l = 0.f;
    for (int e = 0; e < dg; ++e) {
      int j = cols[e];
      const unsigned* kr = (const unsigned*)(k2s + j * 34);
      float s = 0.f;
      #pragma unroll
      for (int m = 0; m < 16; ++m) {
        unsigned u = kr[m];
        s += q[2 * m] * bflo(u) + q[2 * m + 1] * bfhi(u);
      }
      float p = __expf(s * 0.17677669529663688f);
      l += p;
      const unsigned* vr = (const unsigned*)(v2s + j * 34);
      #pragma unroll
      for (int m = 0; m < 16; ++m) {
        unsigned u = vr[m];
        o[2 * m]     += p * bflo(u);
        o[2 * m + 1] += p * bfhi(u);
      }
    }
    float inv = 1.f / l;
    float xr[3];
    #pragma unroll
    for (int a = 0; a < 3; ++a) {
      if (isbf) xr[a] = __bfloat162float(((const __hip_bfloat16*)xraw)[((size_t)g * NN + i) * 3 + a]);
      else      xr[a] = ((const float*)xraw)[((size_t)g * NN + i) * 3 + a];
    }
    float row[32];
    #pragma unroll
    for (int c = 0; c < 32; ++c) row[c] = o[c] * inv;
    row[0] += xr[0]; row[1] += xr[1]; row[2] += xr[2];
    float mean = 0.f;
    #pragma unroll
    for (int c = 0; c < 32; ++c) mean += row[c];
    mean *= (1.f / 32.f);
    float var = 0.f;
    #pragma unroll
    for (int c = 0; c < 32; ++c) { float dd = row[c] - mean; var += dd * dd; }
    var *= (1.f / 32.f);
    float rinv = 1.f / sqrtf(var + 1e-6f);
    float4* so4 = (float4*)(spo + (((size_t)b * NN + i) * 24 + st) * 32);
    #pragma unroll
    for (int k = 0; k < 8; ++k) {
      float4 v;
      v.x = gw[4 * k]     * (row[4 * k]     - mean) * rinv + gw[32 + 4 * k];
      v.y = gw[4 * k + 1] * (row[4 * k + 1] - mean) * rinv + gw[33 + 4 * k];
      v.z = gw[4 * k + 2] * (row[4 * k + 2] - mean) * rinv + gw[34 + 4 * k];
      v.w = gw[4 * k + 3] * (row[4 * k + 3] - mean) * rinv + gw[35 + 4 * k];
      so4[k] = v;
    }
  }
}

// ---------------------------------------------------------------------------
// Temporal transformer + fuse — byte-revert to the R9-measured 117.5 µs
// version (VGPR 68, LDS 26.6 KB): x1s aliased onto aw, wave-0 shfl fuse.
// LDS (dw): t_s 0 [24][32] | q_s 768 [24][65] | k_s 2328 | v_s 3888 |
//           aw 5448 [48][25] (x1s [24][33] aliases @5448 after att) -> 6648.
// ---------------------------------------------------------------------------
__global__ __launch_bounds__(128) void temporal_k(
    const float* __restrict__ sp, const float* __restrict__ tw,
    const unsigned short* __restrict__ probe, void* __restrict__ outp) {
  __shared__ float sm[6648];
  float* t_s = sm;             // [24][32]
  float* q_s = sm + 768;       // [24][65]
  float* k_s = sm + 2328;      // [24][65]
  float* v_s = sm + 3888;      // [24][65]
  float* aw  = sm + 5448;      // [48][25]
  float* x1s = sm + 5448;      // [24][33], aliases aw (aw dead by then)
  float* att = q_s;            // alias: q dead after scores
  float* f1s = k_s;            // alias: k dead after scores ([24][64] linear)
  float* tos = v_s;            // alias: v dead after att    ([24][33])
  const int tid = threadIdx.x;
  bool isbf = detect_bf16(probe);

  const float* twq = tw;            const float* tbq = tw + 2048;
  const float* twk = tw + 2112;     const float* tbk = tw + 4160;
  const float* twv = tw + 4224;     const float* tbv = tw + 6272;
  const float* two = tw + 6336;     const float* tbo = tw + 8384;
  const float* fw1 = tw + 8416;     const float* fb1 = tw + 10464;
  const float* fw2 = tw + 10528;    const float* fb2 = tw + 12576;
  const float* l1g = tw + 12608;    const float* l1b = tw + 12640;
  const float* l2g = tw + 12672;    const float* l2b = tw + 12704;
  const float* fng = tw + 12736;    const float* fnb = tw + 12768;
  const float* fdw = tw + 12800;    const float* fdb = tw + 12832;

  const float4* base4 = (const float4*)(sp + (size_t)blockIdx.x * 768);
  for (int e = tid; e < 192; e += 128) ((float4*)t_s)[e] = base4[e];
  __syncthreads();

  // QKV: thread owns column hk; weights in registers, t_s broadcast reads.
  {
    const int hk = tid & 63, sh = tid >> 6;
    for (int a = 0; a < 3; ++a) {
      const float* W  = (a == 0) ? twq : (a == 1) ? twk : twv;
      const float* Bb = (a == 0) ? tbq : (a == 1) ? tbk : tbv;
      float* dst      = (a == 0) ? q_s : (a == 1) ? k_s : v_s;
      float w[32];
      #pragma unroll
      for (int c = 0; c < 32; ++c) w[c] = W[c * 64 + hk];
      float bias = Bb[hk];
      for (int s = sh * 12; s < sh * 12 + 12; ++s) {
        float acc = bias;
        const float* tr = t_s + s * 32;
        #pragma unroll
        for (int c = 0; c < 32; ++c) acc += tr[c] * w[c];
        dst[s * 65 + hk] = acc;
      }
    }
  }
  __syncthreads();

  // scores + softmax: 96 lanes, 12 keys each, pair-combine via shfl_xor.
  if (tid < 96) {
    const int h = tid / 48, rem = tid % 48, qs = rem >> 1, half = rem & 1;
    const float* qr = q_s + qs * 65 + h * 32;
    float sc[12], l = 0.f;
    #pragma unroll
    for (int k = 0; k < 12; ++k) {
      const float* kr = k_s + (half * 12 + k) * 65 + h * 32;
      float s = 0.f;
      #pragma unroll
      for (int d = 0; d < 32; ++d) s += qr[d] * kr[d];
      sc[k] = __expf(s * 0.17677669529663688f);
      l += sc[k];
    }
    l += __shfl_xor(l, 1);
    float inv = 1.f / l;
    float* ar = aw + (h * 24 + qs) * 25 + half * 12;
    #pragma unroll
    for (int k = 0; k < 12; ++k) ar[k] = sc[k] * inv;
  }
  __syncthreads();

  // attention output (writes att = q_s alias; aw read, dead after this)
  for (int e = tid; e < 1536; e += 128) {
    int qs = e >> 6, hk = e & 63, h = hk >> 5;
    const float* ar = aw + (h * 24 + qs) * 25;
    float a = 0.f;
    #pragma unroll
    for (int ss = 0; ss < 24; ++ss) a += ar[ss] * v_s[ss * 65 + hk];
    att[qs * 65 + hk] = a;
  }
  __syncthreads();

  // output projection + residual (x1s overwrites dead aw region)
  for (int e = tid; e < 768; e += 128) {
    int s = e >> 5, c = e & 31;
    const float* ar = att + s * 65;
    float a = tbo[c];
    #pragma unroll 8
    for (int hk = 0; hk < 64; ++hk) a += ar[hk] * two[hk * 32 + c];
    x1s[s * 33 + c] = t_s[e] + a;
  }
  __syncthreads();
  if (tid < 24) {  // LN1
    float* r = x1s + tid * 33;
    float mean = 0.f;
    for (int c = 0; c < 32; ++c) mean += r[c];
    mean *= (1.f / 32.f);
    float var = 0.f;
    for (int c = 0; c < 32; ++c) { float d = r[c] - mean; var += d * d; }
    var *= (1.f / 32.f);
    float ri = 1.f / sqrtf(var + 1e-6f);
    for (int c = 0; c < 32; ++c) r[c] = l1g[c] * (r[c] - mean) * ri + l1b[c];
  }
  __syncthreads();

  // FF1 + exact gelu (writes f1s = k_s alias)
  {
    const int j = tid & 63, sh = tid >> 6;
    float w[32];
    #pragma unroll
    for (int c = 0; c < 32; ++c) w[c] = fw1[c * 64 + j];
    float bias = fb1[j];
    for (int s = sh * 12; s < sh * 12 + 12; ++s) {
      float acc = bias;
      const float* xr = x1s + s * 33;
      #pragma unroll
      for (int c = 0; c < 32; ++c) acc += xr[c] * w[c];
      f1s[s * 64 + j] = 0.5f * acc * (1.f + erff(acc * 0.70710678118654752f));
    }
  }
  __syncthreads();

  // FF2 + residual (writes tos = v_s alias)
  for (int e = tid; e < 768; e += 128) {
    int s = e >> 5, c = e & 31;
    const float* fr = f1s + s * 64;
    float a = fb2[c];
    #pragma unroll 8
    for (int j = 0; j < 64; ++j) a += fr[j] * fw2[j * 32 + c];
    tos[s * 33 + c] = x1s[s * 33 + c] + a;
  }
  __syncthreads();
  if (tid < 24) {  // LN2
    float* r = tos + tid * 33;
    float mean = 0.f;
    for (int c = 0; c < 32; ++c) mean += r[c];
    mean *= (1.f / 32.f);
    float var = 0.f;
    for (int c = 0; c < 32; ++c) { float d = r[c] - mean; var += d * d; }
    var *= (1.f / 32.f);
    float ri = 1.f / sqrtf(var + 1e-6f);
    for (int c = 0; c < 32; ++c) r[c] = l2g[c] * (r[c] - mean) * ri + l2b[c];
  }
  __syncthreads();

  // fuse: wave 0 lanes 0..31, shfl LN + dense
  if (tid < 32) {
    const int c = tid;
    float ms = 0.f, mt = 0.f;
    #pragma unroll
    for (int s = 0; s < 24; ++s) { ms += t_s[s * 32 + c]; mt += tos[s * 33 + c]; }
    float red = (ms + mt) * (1.f / 24.f);
    float mean = rsum32(red) * (1.f / 32.f);
    float dv = red - mean;
    float var = rsum32(dv * dv) * (1.f / 32.f);
    float ri = 1.f / sqrtf(var + 1e-6f);
    float y = (fng[c] * dv * ri + fnb[c]) * fdw[c];
    float tot = rsum32(y);
    if (c == 0) {
      float acc = tot + fdb[0];
      if (isbf) ((__hip_bfloat16*)outp)[blockIdx.x] = __float2bfloat16(acc);
      else      ((float*)outp)[blockIdx.x] = acc;
    }
  }
}

// ---------------------------------------------------------------------------
extern "C" void kernel_launch(void* const* d_in, const int* in_sizes, int n_in,
                              void* d_out, int out_size, void* d_ws, size_t ws_size,
                              hipStream_t stream) {
  static const int wsizes[34] = {
      192, 64, 192, 64, 192, 64,
      2048, 32, 2048, 32, 2048, 32,
      32, 32,
      2048, 64, 2048, 64, 2048, 64, 2048, 32,
      2048, 64, 2048, 32,
      32, 32, 32, 32, 32, 32,
      32, 1};
  WTab wt;
  int off = 0;
  for (int i = 0; i < 34; ++i) { wt.p[i] = d_in[i + 2]; wt.off[i] = off; off += wsizes[i]; }
  wt.off[34] = off;  // 19905

  char* ws = (char*)d_ws;
  float* convw = (float*)ws;                       // 19905 f
  int*   colp  = (int*)(ws + 81920);               // 400*64
  int*   degp  = (int*)(ws + 184320);              // 400
  unsigned short* h1b = (unsigned short*)(ws + 196608);    // 9.83 MB
  unsigned short* q2b = (unsigned short*)(ws + 10027008);  // 4.92 MB
  float*          spo = (float*)(ws + 14942208);           // 9.83 MB (h1b live in projattn)

  const float* g1  = convw;
  const float* g2  = convw + 768;
  const float* spw = convw + 7008;
  const float* twp = convw + 7072;
  const unsigned short* probe = (const unsigned short*)d_in[0];

  hipLaunchKernelGGL(prep_k, dim3(140), dim3(256), 0, stream, wt, d_in[1], probe,
                     convw, colp, degp);
  hipLaunchKernelGGL(gat1_k, dim3(192, 2), dim3(256), 0, stream, d_in[0], probe,
                     g1, (const int*)colp, (const int*)degp, h1b);
  hipLaunchKernelGGL(projattn_k, dim3(192), dim3(256), 0, stream, d_in[0], probe,
                     (const unsigned short*)h1b, g2, spw, (const int*)colp,
                     (const int*)degp, q2b, spo);
  hipLaunchKernelGGL(temporal_k, dim3(3200), dim3(128), 0, stream,
                     (const float*)spo, twp, probe, d_out);
}

// Round 12
// 299.829 us; speedup vs baseline: 1.1542x; 1.1542x over previous
//
#include <hip/hip_runtime.h>
#include <hip/hip_bf16.h>

#define NN 400
#define KMAX 64

struct WTab {
  const void* p[34];
  int off[35];
};

__device__ __forceinline__ float bflo(unsigned u) {
  union { unsigned i; float f; } x; x.i = u << 16; return x.f;
}
__device__ __forceinline__ float bfhi(unsigned u) {
  union { unsigned i; float f; } x; x.i = u & 0xffff0000u; return x.f;
}
__device__ __forceinline__ unsigned short f2bf(float f) {
  __hip_bfloat16 b = __float2bfloat16(f);
  return *reinterpret_cast<unsigned short*>(&b);
}
__device__ __forceinline__ unsigned packbf(float a, float b) {
  return (unsigned)f2bf(a) | ((unsigned)f2bf(b) << 16);
}
// Per-wave dtype sniff: bf16 data has plausible N(0,1) exponents at even u16s.
__device__ __forceinline__ bool detect_bf16(const unsigned short* probe) {
  int lane = threadIdx.x & 63;
  unsigned short u = probe[lane * 2];
  int e = (u >> 7) & 0xFF;
  bool plaus = (u == 0) || (e >= 112 && e <= 132);
  return __popcll(__ballot(plaus)) >= 48;
}
__device__ __forceinline__ float rsum32(float v) {
  v += __shfl_xor(v, 1); v += __shfl_xor(v, 2); v += __shfl_xor(v, 4);
  v += __shfl_xor(v, 8); v += __shfl_xor(v, 16); return v;
}

// ---------------------------------------------------------------------------
// prep: blocks 0..39 convert the 34 weight tensors (19905 elems) to fp32;
// blocks 40..139 build CSR (4 adjacency rows per block, one per wave).
// ---------------------------------------------------------------------------
__global__ __launch_bounds__(256) void prep_k(
    WTab wt, const void* __restrict__ adj,
    const unsigned short* __restrict__ probe, float* __restrict__ dst,
    int* __restrict__ colp, int* __restrict__ degp) {
  bool isbf = detect_bf16(probe);
  const int tid = threadIdx.x;
  if (blockIdx.x < 40) {
    int total = wt.off[34];
    for (int i = blockIdx.x * 256 + tid; i < total; i += 40 * 256) {
      int lo = 0, hi = 33;
      while (lo < hi) {
        int mid = (lo + hi + 1) >> 1;
        if (i >= wt.off[mid]) lo = mid; else hi = mid - 1;
      }
      int rel = i - wt.off[lo];
      float v;
      if (isbf) v = __bfloat162float(((const __hip_bfloat16*)wt.p[lo])[rel]);
      else      v = ((const float*)wt.p[lo])[rel];
      dst[i] = v;
    }
  } else {
    int row = (blockIdx.x - 40) * 4 + (tid >> 6);
    int lane = tid & 63;
    int base = 0;
    for (int j0 = 0; j0 < NN; j0 += 64) {
      int j = j0 + lane;
      bool nz;
      if (isbf) nz = (j < NN) && ((const unsigned short*)adj)[row * NN + j] != 0;
      else      nz = (j < NN) && ((const float*)adj)[row * NN + j] != 0.0f;
      unsigned long long m = __ballot(nz);
      int offl = __popcll(m & ((1ull << lane) - 1ull));
      if (nz) {
        int pidx = base + offl;
        if (pidx < KMAX) colp[row * KMAX + pidx] = j;
      }
      base += __popcll(m);
    }
    if (lane == 0) degp[row] = base < KMAX ? base : KMAX;
  }
}

// ---------------------------------------------------------------------------
// GAT1 + GAT2 Q/K/V projection, fused. grid (192 graphs, 2 node-halves),
// 200 nodes/block (one per thread). Phase 1: collapsed GAT1 (s_ij = xi·M xj
// + ci + dj + s0) -> per-node weighted-mean 3-vec b_h. Phase 2 (yhf/xsf dead,
// barrier): thread writes its node's h1[d]=relu(Wv1·b+bias) bf16 into LDS
// transposed ht[64 d][208] (uint4-aligned rows). Phase 3: gat2_proj's exact
// thread mapping (c=tid&31, ng=tid>>5, qa/ka/va[8]) -> q2b/k2g/v2g global.
// Numerics identical to the standalone proj (h1 was bf16 there too).
// LDS: xsf 6400 + yhf 25600 + w1s 3072 + cf 256 = 35328 B (ht 26624 aliases
// xsf+yhf). 4 blocks/CU capacity, 384 blocks.
// ---------------------------------------------------------------------------
__global__ __launch_bounds__(256) void gat1proj_k(
    const void* __restrict__ xraw, const unsigned short* __restrict__ probe,
    const float* __restrict__ g1, const float* __restrict__ g2,
    const int* __restrict__ colp, const int* __restrict__ degp,
    unsigned short* __restrict__ q2b, unsigned short* __restrict__ k2g,
    unsigned short* __restrict__ v2g) {
  __shared__ __align__(16) float smf[8832];
  float* xsf = smf;                       // [400*4]
  float* yhf = smf + 1600;                // [6400]
  float* w1s = smf + 8000;                // [768]
  float* cf  = smf + 8768;                // [64]
  unsigned short* ht = (unsigned short*)smf;  // [64][208] u16, after barrier
  const int tid = threadIdx.x;
  const int g = blockIdx.x;
  const int i0 = blockIdx.y * 200;
  bool isbf = detect_bf16(probe);

  for (int e = tid; e < 768; e += 256) w1s[e] = g1[e];
  for (int e = tid; e < NN; e += 256) xsf[e * 4 + 3] = 0.f;
  for (int e = tid; e < NN * 3; e += 256) {
    int j = e / 3, a = e - j * 3;
    float v;
    if (isbf) v = __bfloat162float(((const __hip_bfloat16*)xraw)[g * NN * 3 + e]);
    else      v = ((const float*)xraw)[g * NN * 3 + e];
    xsf[j * 4 + a] = v;
  }
  __syncthreads();

  if (tid < 64) {  // collapsed GAT1 coefficients
    int h = tid >> 4, t = tid & 15, co = h * 16;
    float acc = 0.f;
    if (t < 9) {
      int a = t / 3, b = t - (t / 3) * 3;
      for (int c = 0; c < 16; ++c) acc += w1s[a * 64 + co + c] * w1s[256 + b * 64 + co + c];
    } else if (t < 12) {
      int a = t - 9;
      for (int c = 0; c < 16; ++c) acc += w1s[a * 64 + co + c] * w1s[448 + co + c];
    } else if (t < 15) {
      int b = t - 12;
      for (int c = 0; c < 16; ++c) acc += w1s[256 + b * 64 + co + c] * w1s[192 + co + c];
    } else {
      for (int c = 0; c < 16; ++c) acc += w1s[192 + co + c] * w1s[448 + co + c];
    }
    cf[h * 16 + t] = acc;
  }
  __syncthreads();

  for (int e = tid; e < NN * 4; e += 256) {  // per (node, head) aux
    int j = e >> 2, h = e & 3;
    const float* bse = cf + h * 16;
    float x0 = xsf[j * 4], x1 = xsf[j * 4 + 1], x2 = xsf[j * 4 + 2];
    float* y = yhf + (h * NN + j) * 4;
    y[0] = bse[0] * x0 + bse[1] * x1 + bse[2] * x2;
    y[1] = bse[3] * x0 + bse[4] * x1 + bse[5] * x2;
    y[2] = bse[6] * x0 + bse[7] * x1 + bse[8] * x2;
    y[3] = bse[12] * x0 + bse[13] * x1 + bse[14] * x2 + bse[15];
  }
  __syncthreads();

  // ---- Phase 1: neighbor loop, one node per thread (200 < 256) ----
  const float4* xs4 = (const float4*)xsf;
  const float4* yh4 = (const float4*)yhf;
  float bx[4], by[4], bz[4];
  const bool act = tid < 200;
  const int i = i0 + tid;
  if (act) {
    float4 xi = xs4[i];
    float ch[4];
    #pragma unroll
    for (int h = 0; h < 4; ++h)
      ch[h] = cf[h * 16 + 9] * xi.x + cf[h * 16 + 10] * xi.y + cf[h * 16 + 11] * xi.z;
    float l[4] = {0.f, 0.f, 0.f, 0.f};
    #pragma unroll
    for (int h = 0; h < 4; ++h) { bx[h] = 0.f; by[h] = 0.f; bz[h] = 0.f; }
    int dg = degp[i];
    const int* cols = colp + i * KMAX;
    for (int e = 0; e < dg; ++e) {
      int j = cols[e];
      float4 xj = xs4[j];
      #pragma unroll
      for (int h = 0; h < 4; ++h) {
        float4 y = yh4[h * NN + j];
        float s = (xi.x * y.x + xi.y * y.y + xi.z * y.z + y.w + ch[h]) * 0.25f;
        float p = __expf(s);
        l[h] += p;
        bx[h] += p * xj.x; by[h] += p * xj.y; bz[h] += p * xj.z;
      }
    }
    #pragma unroll
    for (int h = 0; h < 4; ++h) {
      float inv = 1.f / l[h];
      bx[h] *= inv; by[h] *= inv; bz[h] *= inv;
    }
  }
  __syncthreads();  // xsf/yhf dead; ht overlays them

  // ---- Phase 2: h1 (bf16) transposed into ht[d][local node] ----
  if (act) {
    #pragma unroll
    for (int h = 0; h < 4; ++h) {
      int co = h * 16;
      #pragma unroll
      for (int c = 0; c < 16; ++c) {
        int d = co + c;
        float hd = fmaxf(bx[h] * w1s[512 + d] + by[h] * w1s[576 + d] +
                         bz[h] * w1s[640 + d] + w1s[704 + d], 0.f);
        ht[d * 208 + tid] = f2bf(hd);
      }
    }
  }
  __syncthreads();

  // ---- Phase 3: gat2_proj thread mapping over the 200 local nodes ----
  {
    const int c = tid & 31, ng = tid >> 5;
    const float* wq = g2;
    const float* wk = g2 + 2080;
    const float* wv = g2 + 4160;
    const float bq = g2[2048 + c], bk = g2[4128 + c], bv = g2[6208 + c];
    for (int base = 0; base < 200; base += 64) {
      const int nb = base + ng * 8;
      if (nb < 200) {
        float qa[8], ka[8], va[8];
        #pragma unroll
        for (int k = 0; k < 8; ++k) { qa[k] = bq; ka[k] = bk; va[k] = bv; }
        for (int d = 0; d < 64; ++d) {
          float wqv = wq[d * 32 + c], wkv = wk[d * 32 + c], wvv = wv[d * 32 + c];
          uint4 hv4 = *(const uint4*)(ht + d * 208 + nb);
          unsigned uu[4] = {hv4.x, hv4.y, hv4.z, hv4.w};
          #pragma unroll
          for (int m = 0; m < 4; ++m) {
            float h0 = bflo(uu[m]), h1v = bfhi(uu[m]);
            qa[2*m] += h0 * wqv;   qa[2*m+1] += h1v * wqv;
            ka[2*m] += h0 * wkv;   ka[2*m+1] += h1v * wkv;
            va[2*m] += h0 * wvv;   va[2*m+1] += h1v * wvv;
          }
        }
        #pragma unroll
        for (int k = 0; k < 8; ++k) {
          size_t gn = (size_t)g * NN + i0 + nb + k;
          q2b[gn * 32 + c] = f2bf(qa[k]);
          k2g[gn * 32 + c] = f2bf(ka[k]);
          v2g[gn * 32 + c] = f2bf(va[k]);
        }
      }
    }
  }
}

// ---------------------------------------------------------------------------
// GAT2 attention + residual + LN. grid (192, 2): 200 nodes per block; full
// K/V staged bf16 (uint2), 80B rows. spo written [b][n][s][32].
// ---------------------------------------------------------------------------
__global__ __launch_bounds__(256) void gat2_attn_k(
    const void* __restrict__ xraw, const unsigned short* __restrict__ probe,
    const unsigned short* __restrict__ q2b, const unsigned short* __restrict__ k2g,
    const unsigned short* __restrict__ v2g, const float* __restrict__ spw,
    const int* __restrict__ colp, const int* __restrict__ degp,
    float* __restrict__ spo) {
  __shared__ unsigned short k2s[NN * 40];
  __shared__ unsigned short v2s[NN * 40];
  __shared__ float gw[64];
  const int tid = threadIdx.x;
  const int g = blockIdx.x;
  bool isbf = detect_bf16(probe);
  if (tid < 64) gw[tid] = spw[tid];
  for (int e = tid; e < 3200; e += 256) {
    uint2 uk = ((const uint2*)k2g)[g * 3200 + e];
    uint2 uv = ((const uint2*)v2g)[g * 3200 + e];
    int n = e >> 3, c = (e & 7) * 2;
    *(uint2*)((unsigned*)k2s + n * 20 + c) = uk;
    *(uint2*)((unsigned*)v2s + n * 20 + c) = uv;
  }
  __syncthreads();
  const int b = g / 24, st = g % 24;
  const int i0 = blockIdx.y * 200;
  for (int i = i0 + tid; i < i0 + 200; i += 256) {
    const uint4* qp = (const uint4*)(q2b + ((size_t)g * NN + i) * 32);
    uint4 qw[4] = {qp[0], qp[1], qp[2], qp[3]};
    float q[32], o[32];
    #pragma unroll
    for (int t = 0; t < 4; ++t) {
      unsigned uu[4] = {qw[t].x, qw[t].y, qw[t].z, qw[t].w};
      #pragma unroll
      for (int m = 0; m < 4; ++m) {
        q[t * 8 + 2 * m] = bflo(uu[m]); q[t * 8 + 2 * m + 1] = bfhi(uu[m]);
      }
    }
    #pragma unroll
    for (int c = 0; c < 32; ++c) o[c] = 0.f;
    int dg = degp[i];
    const int* cols = colp + i * KMAX;
    float l = 0.f;
    for (int e = 0; e < dg; ++e) {
      int j = cols[e];
      const uint4* kr = (const uint4*)(k2s + j * 40);
      const uint4* vr = (const uint4*)(v2s + j * 40);
      float s = 0.f;
      #pragma unroll
      for (int t = 0; t < 4; ++t) {
        uint4 kk = kr[t];
        unsigned uu[4] = {kk.x, kk.y, kk.z, kk.w};
        #pragma unroll
        for (int m = 0; m < 4; ++m)
          s += q[t * 8 + 2 * m] * bflo(uu[m]) + q[t * 8 + 2 * m + 1] * bfhi(uu[m]);
      }
      float p = __expf(s * 0.17677669529663688f);
      l += p;
      #pragma unroll
      for (int t = 0; t < 4; ++t) {
        uint4 vv = vr[t];
        unsigned uu[4] = {vv.x, vv.y, vv.z, vv.w};
        #pragma unroll
        for (int m = 0; m < 4; ++m) {
          o[t * 8 + 2 * m]     += p * bflo(uu[m]);
          o[t * 8 + 2 * m + 1] += p * bfhi(uu[m]);
        }
      }
    }
    float inv = 1.f / l;
    float xr[3];
    #pragma unroll
    for (int a = 0; a < 3; ++a) {
      if (isbf) xr[a] = __bfloat162float(((const __hip_bfloat16*)xraw)[((size_t)g * NN + i) * 3 + a]);
      else      xr[a] = ((const float*)xraw)[((size_t)g * NN + i) * 3 + a];
    }
    float row[32];
    #pragma unroll
    for (int c = 0; c < 32; ++c) row[c] = o[c] * inv;
    row[0] += xr[0]; row[1] += xr[1]; row[2] += xr[2];
    float mean = 0.f;
    #pragma unroll
    for (int c = 0; c < 32; ++c) mean += row[c];
    mean *= (1.f / 32.f);
    float var = 0.f;
    #pragma unroll
    for (int c = 0; c < 32; ++c) { float dd = row[c] - mean; var += dd * dd; }
    var *= (1.f / 32.f);
    float rinv = 1.f / sqrtf(var + 1e-6f);
    float4* so4 = (float4*)(spo + (((size_t)b * NN + i) * 24 + st) * 32);
    #pragma unroll
    for (int k = 0; k < 8; ++k) {
      float4 v;
      v.x = gw[4 * k]     * (row[4 * k]     - mean) * rinv + gw[32 + 4 * k];
      v.y = gw[4 * k + 1] * (row[4 * k + 1] - mean) * rinv + gw[33 + 4 * k];
      v.z = gw[4 * k + 2] * (row[4 * k + 2] - mean) * rinv + gw[34 + 4 * k];
      v.w = gw[4 * k + 3] * (row[4 * k + 3] - mean) * rinv + gw[35 + 4 * k];
      so4[k] = v;
    }
  }
}

// ---------------------------------------------------------------------------
// Temporal transformer + fuse — R9's measured-117.5µs version (VGPR 68,
// LDS 26.6 KB): x1s aliased onto aw, wave-0 shfl fuse.
// LDS (dw): t_s 0 [24][32] | q_s 768 [24][65] | k_s 2328 | v_s 3888 |
//           aw 5448 [48][25] (x1s [24][33] aliases @5448 after att) -> 6648.
// ---------------------------------------------------------------------------
__global__ __launch_bounds__(128) void temporal_k(
    const float* __restrict__ sp, const float* __restrict__ tw,
    const unsigned short* __restrict__ probe, void* __restrict__ outp) {
  __shared__ float sm[6648];
  float* t_s = sm;             // [24][32]
  float* q_s = sm + 768;       // [24][65]
  float* k_s = sm + 2328;      // [24][65]
  float* v_s = sm + 3888;      // [24][65]
  float* aw  = sm + 5448;      // [48][25]
  float* x1s = sm + 5448;      // [24][33], aliases aw (aw dead by then)
  float* att = q_s;            // alias: q dead after scores
  float* f1s = k_s;            // alias: k dead after scores ([24][64] linear)
  float* tos = v_s;            // alias: v dead after att    ([24][33])
  const int tid = threadIdx.x;
  bool isbf = detect_bf16(probe);

  const float* twq = tw;            const float* tbq = tw + 2048;
  const float* twk = tw + 2112;     const float* tbk = tw + 4160;
  const float* twv = tw + 4224;     const float* tbv = tw + 6272;
  const float* two = tw + 6336;     const float* tbo = tw + 8384;
  const float* fw1 = tw + 8416;     const float* fb1 = tw + 10464;
  const float* fw2 = tw + 10528;    const float* fb2 = tw + 12576;
  const float* l1g = tw + 12608;    const float* l1b = tw + 12640;
  const float* l2g = tw + 12672;    const float* l2b = tw + 12704;
  const float* fng = tw + 12736;    const float* fnb = tw + 12768;
  const float* fdw = tw + 12800;    const float* fdb = tw + 12832;

  const float4* base4 = (const float4*)(sp + (size_t)blockIdx.x * 768);
  for (int e = tid; e < 192; e += 128) ((float4*)t_s)[e] = base4[e];
  __syncthreads();

  // QKV: thread owns column hk; weights in registers, t_s broadcast reads.
  {
    const int hk = tid & 63, sh = tid >> 6;
    for (int a = 0; a < 3; ++a) {
      const float* W  = (a == 0) ? twq : (a == 1) ? twk : twv;
      const float* Bb = (a == 0) ? tbq : (a == 1) ? tbk : tbv;
      float* dst      = (a == 0) ? q_s : (a == 1) ? k_s : v_s;
      float w[32];
      #pragma unroll
      for (int c = 0; c < 32; ++c) w[c] = W[c * 64 + hk];
      float bias = Bb[hk];
      for (int s = sh * 12; s < sh * 12 + 12; ++s) {
        float acc = bias;
        const float* tr = t_s + s * 32;
        #pragma unroll
        for (int c = 0; c < 32; ++c) acc += tr[c] * w[c];
        dst[s * 65 + hk] = acc;
      }
    }
  }
  __syncthreads();

  // scores + softmax: 96 lanes, 12 keys each, pair-combine via shfl_xor.
  if (tid < 96) {
    const int h = tid / 48, rem = tid % 48, qs = rem >> 1, half = rem & 1;
    const float* qr = q_s + qs * 65 + h * 32;
    float sc[12], l = 0.f;
    #pragma unroll
    for (int k = 0; k < 12; ++k) {
      const float* kr = k_s + (half * 12 + k) * 65 + h * 32;
      float s = 0.f;
      #pragma unroll
      for (int d = 0; d < 32; ++d) s += qr[d] * kr[d];
      sc[k] = __expf(s * 0.17677669529663688f);
      l += sc[k];
    }
    l += __shfl_xor(l, 1);
    float inv = 1.f / l;
    float* ar = aw + (h * 24 + qs) * 25 + half * 12;
    #pragma unroll
    for (int k = 0; k < 12; ++k) ar[k] = sc[k] * inv;
  }
  __syncthreads();

  // attention output (writes att = q_s alias; aw read, dead after this)
  for (int e = tid; e < 1536; e += 128) {
    int qs = e >> 6, hk = e & 63, h = hk >> 5;
    const float* ar = aw + (h * 24 + qs) * 25;
    float a = 0.f;
    #pragma unroll
    for (int ss = 0; ss < 24; ++ss) a += ar[ss] * v_s[ss * 65 + hk];
    att[qs * 65 + hk] = a;
  }
  __syncthreads();

  // output projection + residual (x1s overwrites dead aw region)
  for (int e = tid; e < 768; e += 128) {
    int s = e >> 5, c = e & 31;
    const float* ar = att + s * 65;
    float a = tbo[c];
    #pragma unroll 8
    for (int hk = 0; hk < 64; ++hk) a += ar[hk] * two[hk * 32 + c];
    x1s[s * 33 + c] = t_s[e] + a;
  }
  __syncthreads();
  if (tid < 24) {  // LN1
    float* r = x1s + tid * 33;
    float mean = 0.f;
    for (int c = 0; c < 32; ++c) mean += r[c];
    mean *= (1.f / 32.f);
    float var = 0.f;
    for (int c = 0; c < 32; ++c) { float d = r[c] - mean; var += d * d; }
    var *= (1.f / 32.f);
    float ri = 1.f / sqrtf(var + 1e-6f);
    for (int c = 0; c < 32; ++c) r[c] = l1g[c] * (r[c] - mean) * ri + l1b[c];
  }
  __syncthreads();

  // FF1 + exact gelu (writes f1s = k_s alias)
  {
    const int j = tid & 63, sh = tid >> 6;
    float w[32];
    #pragma unroll
    for (int c = 0; c < 32; ++c) w[c] = fw1[c * 64 + j];
    float bias = fb1[j];
    for (int s = sh * 12; s < sh * 12 + 12; ++s) {
      float acc = bias;
      const float* xr = x1s + s * 33;
      #pragma unroll
      for (int c = 0; c < 32; ++c) acc += xr[c] * w[c];
      f1s[s * 64 + j] = 0.5f * acc * (1.f + erff(acc * 0.70710678118654752f));
    }
  }
  __syncthreads();

  // FF2 + residual (writes tos = v_s alias)
  for (int e = tid; e < 768; e += 128) {
    int s = e >> 5, c = e & 31;
    const float* fr = f1s + s * 64;
    float a = fb2[c];
    #pragma unroll 8
    for (int j = 0; j < 64; ++j) a += fr[j] * fw2[j * 32 + c];
    tos[s * 33 + c] = x1s[s * 33 + c] + a;
  }
  __syncthreads();
  if (tid < 24) {  // LN2
    float* r = tos + tid * 33;
    float mean = 0.f;
    for (int c = 0; c < 32; ++c) mean += r[c];
    mean *= (1.f / 32.f);
    float var = 0.f;
    for (int c = 0; c < 32; ++c) { float d = r[c] - mean; var += d * d; }
    var *= (1.f / 32.f);
    float ri = 1.f / sqrtf(var + 1e-6f);
    for (int c = 0; c < 32; ++c) r[c] = l2g[c] * (r[c] - mean) * ri + l2b[c];
  }
  __syncthreads();

  // fuse: wave 0 lanes 0..31, shfl LN + dense
  if (tid < 32) {
    const int c = tid;
    float ms = 0.f, mt = 0.f;
    #pragma unroll
    for (int s = 0; s < 24; ++s) { ms += t_s[s * 32 + c]; mt += tos[s * 33 + c]; }
    float red = (ms + mt) * (1.f / 24.f);
    float mean = rsum32(red) * (1.f / 32.f);
    float dv = red - mean;
    float var = rsum32(dv * dv) * (1.f / 32.f);
    float ri = 1.f / sqrtf(var + 1e-6f);
    float y = (fng[c] * dv * ri + fnb[c]) * fdw[c];
    float tot = rsum32(y);
    if (c == 0) {
      float acc = tot + fdb[0];
      if (isbf) ((__hip_bfloat16*)outp)[blockIdx.x] = __float2bfloat16(acc);
      else      ((float*)outp)[blockIdx.x] = acc;
    }
  }
}

// ---------------------------------------------------------------------------
extern "C" void kernel_launch(void* const* d_in, const int* in_sizes, int n_in,
                              void* d_out, int out_size, void* d_ws, size_t ws_size,
                              hipStream_t stream) {
  static const int wsizes[34] = {
      192, 64, 192, 64, 192, 64,
      2048, 32, 2048, 32, 2048, 32,
      32, 32,
      2048, 64, 2048, 64, 2048, 64, 2048, 32,
      2048, 64, 2048, 32,
      32, 32, 32, 32, 32, 32,
      32, 1};
  WTab wt;
  int off = 0;
  for (int i = 0; i < 34; ++i) { wt.p[i] = d_in[i + 2]; wt.off[i] = off; off += wsizes[i]; }
  wt.off[34] = off;  // 19905

  char* ws = (char*)d_ws;
  float* convw = (float*)ws;                               // 19905 f
  int*   colp  = (int*)(ws + 81920);                       // 400*64
  int*   degp  = (int*)(ws + 184320);                      // 400
  unsigned short* q2b = (unsigned short*)(ws + 196608);    // 4.92 MB
  unsigned short* k2g = (unsigned short*)(ws + 5242880);   // 4.92 MB
  unsigned short* v2g = (unsigned short*)(ws + 10289152);  // 4.92 MB
  float*          spo = (float*)(ws + 15335424);           // 9.83 MB -> ~25.2 MB

  const float* g1  = convw;
  const float* g2  = convw + 768;
  const float* spw = convw + 7008;
  const float* twp = convw + 7072;
  const unsigned short* probe = (const unsigned short*)d_in[0];

  hipLaunchKernelGGL(prep_k, dim3(140), dim3(256), 0, stream, wt, d_in[1], probe,
                     convw, colp, degp);
  hipLaunchKernelGGL(gat1proj_k, dim3(192, 2), dim3(256), 0, stream, d_in[0],
                     probe, g1, g2, (const int*)colp, (const int*)degp,
                     q2b, k2g, v2g);
  hipLaunchKernelGGL(gat2_attn_k, dim3(192, 2), dim3(256), 0, stream, d_in[0],
                     probe, (const unsigned short*)q2b, (const unsigned short*)k2g,
                     (const unsigned short*)v2g, spw, (const int*)colp,
                     (const int*)degp, spo);
  hipLaunchKernelGGL(temporal_k, dim3(3200), dim3(128), 0, stream,
                     (const float*)spo, twp, probe, d_out);
}

// Round 13
// 290.065 us; speedup vs baseline: 1.1930x; 1.0337x over previous
//
#include <hip/hip_runtime.h>
#include <hip/hip_bf16.h>

#define NN 400
#define KMAX 64

struct WTab {
  const void* p[34];
  int off[35];
};

__device__ __forceinline__ float bflo(unsigned u) {
  union { unsigned i; float f; } x; x.i = u << 16; return x.f;
}
__device__ __forceinline__ float bfhi(unsigned u) {
  union { unsigned i; float f; } x; x.i = u & 0xffff0000u; return x.f;
}
__device__ __forceinline__ unsigned short f2bf(float f) {
  __hip_bfloat16 b = __float2bfloat16(f);
  return *reinterpret_cast<unsigned short*>(&b);
}
__device__ __forceinline__ unsigned packbf(float a, float b) {
  return (unsigned)f2bf(a) | ((unsigned)f2bf(b) << 16);
}
// Per-wave dtype sniff: bf16 data has plausible N(0,1) exponents at even u16s.
__device__ __forceinline__ bool detect_bf16(const unsigned short* probe) {
  int lane = threadIdx.x & 63;
  unsigned short u = probe[lane * 2];
  int e = (u >> 7) & 0xFF;
  bool plaus = (u == 0) || (e >= 112 && e <= 132);
  return __popcll(__ballot(plaus)) >= 48;
}
__device__ __forceinline__ float rsum32(float v) {
  v += __shfl_xor(v, 1); v += __shfl_xor(v, 2); v += __shfl_xor(v, 4);
  v += __shfl_xor(v, 8); v += __shfl_xor(v, 16); return v;
}

// ---------------------------------------------------------------------------
// prep: blocks 0..39 convert the 34 weight tensors (19905 elems) to fp32;
// blocks 40..139 build CSR (4 adjacency rows per block, one per wave).
// ---------------------------------------------------------------------------
__global__ __launch_bounds__(256) void prep_k(
    WTab wt, const void* __restrict__ adj,
    const unsigned short* __restrict__ probe, float* __restrict__ dst,
    int* __restrict__ colp, int* __restrict__ degp) {
  bool isbf = detect_bf16(probe);
  const int tid = threadIdx.x;
  if (blockIdx.x < 40) {
    int total = wt.off[34];
    for (int i = blockIdx.x * 256 + tid; i < total; i += 40 * 256) {
      int lo = 0, hi = 33;
      while (lo < hi) {
        int mid = (lo + hi + 1) >> 1;
        if (i >= wt.off[mid]) lo = mid; else hi = mid - 1;
      }
      int rel = i - wt.off[lo];
      float v;
      if (isbf) v = __bfloat162float(((const __hip_bfloat16*)wt.p[lo])[rel]);
      else      v = ((const float*)wt.p[lo])[rel];
      dst[i] = v;
    }
  } else {
    int row = (blockIdx.x - 40) * 4 + (tid >> 6);
    int lane = tid & 63;
    int base = 0;
    for (int j0 = 0; j0 < NN; j0 += 64) {
      int j = j0 + lane;
      bool nz;
      if (isbf) nz = (j < NN) && ((const unsigned short*)adj)[row * NN + j] != 0;
      else      nz = (j < NN) && ((const float*)adj)[row * NN + j] != 0.0f;
      unsigned long long m = __ballot(nz);
      int offl = __popcll(m & ((1ull << lane) - 1ull));
      if (nz) {
        int pidx = base + offl;
        if (pidx < KMAX) colp[row * KMAX + pidx] = j;
      }
      base += __popcll(m);
    }
    if (lane == 0) degp[row] = base < KMAX ? base : KMAX;
  }
}

// ---------------------------------------------------------------------------
// GAT1 + GAT2 Q/K/V projection, fused (R12, measured good). grid (192, 2),
// 200 nodes/block (one per thread). Phase 1: collapsed GAT1 -> b_h 3-vec.
// Phase 2: h1 bf16 transposed into ht[64][208] (overlays dead xsf/yhf).
// Phase 3: gat2_proj thread mapping -> q2b/k2g/v2g global.
// ---------------------------------------------------------------------------
__global__ __launch_bounds__(256) void gat1proj_k(
    const void* __restrict__ xraw, const unsigned short* __restrict__ probe,
    const float* __restrict__ g1, const float* __restrict__ g2,
    const int* __restrict__ colp, const int* __restrict__ degp,
    unsigned short* __restrict__ q2b, unsigned short* __restrict__ k2g,
    unsigned short* __restrict__ v2g) {
  __shared__ __align__(16) float smf[8832];
  float* xsf = smf;                       // [400*4]
  float* yhf = smf + 1600;                // [6400]
  float* w1s = smf + 8000;                // [768]
  float* cf  = smf + 8768;                // [64]
  unsigned short* ht = (unsigned short*)smf;  // [64][208] u16, after barrier
  const int tid = threadIdx.x;
  const int g = blockIdx.x;
  const int i0 = blockIdx.y * 200;
  bool isbf = detect_bf16(probe);

  for (int e = tid; e < 768; e += 256) w1s[e] = g1[e];
  for (int e = tid; e < NN; e += 256) xsf[e * 4 + 3] = 0.f;
  for (int e = tid; e < NN * 3; e += 256) {
    int j = e / 3, a = e - j * 3;
    float v;
    if (isbf) v = __bfloat162float(((const __hip_bfloat16*)xraw)[g * NN * 3 + e]);
    else      v = ((const float*)xraw)[g * NN * 3 + e];
    xsf[j * 4 + a] = v;
  }
  __syncthreads();

  if (tid < 64) {  // collapsed GAT1 coefficients
    int h = tid >> 4, t = tid & 15, co = h * 16;
    float acc = 0.f;
    if (t < 9) {
      int a = t / 3, b = t - (t / 3) * 3;
      for (int c = 0; c < 16; ++c) acc += w1s[a * 64 + co + c] * w1s[256 + b * 64 + co + c];
    } else if (t < 12) {
      int a = t - 9;
      for (int c = 0; c < 16; ++c) acc += w1s[a * 64 + co + c] * w1s[448 + co + c];
    } else if (t < 15) {
      int b = t - 12;
      for (int c = 0; c < 16; ++c) acc += w1s[256 + b * 64 + co + c] * w1s[192 + co + c];
    } else {
      for (int c = 0; c < 16; ++c) acc += w1s[192 + co + c] * w1s[448 + co + c];
    }
    cf[h * 16 + t] = acc;
  }
  __syncthreads();

  for (int e = tid; e < NN * 4; e += 256) {  // per (node, head) aux
    int j = e >> 2, h = e & 3;
    const float* bse = cf + h * 16;
    float x0 = xsf[j * 4], x1 = xsf[j * 4 + 1], x2 = xsf[j * 4 + 2];
    float* y = yhf + (h * NN + j) * 4;
    y[0] = bse[0] * x0 + bse[1] * x1 + bse[2] * x2;
    y[1] = bse[3] * x0 + bse[4] * x1 + bse[5] * x2;
    y[2] = bse[6] * x0 + bse[7] * x1 + bse[8] * x2;
    y[3] = bse[12] * x0 + bse[13] * x1 + bse[14] * x2 + bse[15];
  }
  __syncthreads();

  // ---- Phase 1: neighbor loop, one node per thread (200 < 256) ----
  const float4* xs4 = (const float4*)xsf;
  const float4* yh4 = (const float4*)yhf;
  float bx[4], by[4], bz[4];
  const bool act = tid < 200;
  const int i = i0 + tid;
  if (act) {
    float4 xi = xs4[i];
    float ch[4];
    #pragma unroll
    for (int h = 0; h < 4; ++h)
      ch[h] = cf[h * 16 + 9] * xi.x + cf[h * 16 + 10] * xi.y + cf[h * 16 + 11] * xi.z;
    float l[4] = {0.f, 0.f, 0.f, 0.f};
    #pragma unroll
    for (int h = 0; h < 4; ++h) { bx[h] = 0.f; by[h] = 0.f; bz[h] = 0.f; }
    int dg = degp[i];
    const int* cols = colp + i * KMAX;
    for (int e = 0; e < dg; ++e) {
      int j = cols[e];
      float4 xj = xs4[j];
      #pragma unroll
      for (int h = 0; h < 4; ++h) {
        float4 y = yh4[h * NN + j];
        float s = (xi.x * y.x + xi.y * y.y + xi.z * y.z + y.w + ch[h]) * 0.25f;
        float p = __expf(s);
        l[h] += p;
        bx[h] += p * xj.x; by[h] += p * xj.y; bz[h] += p * xj.z;
      }
    }
    #pragma unroll
    for (int h = 0; h < 4; ++h) {
      float inv = 1.f / l[h];
      bx[h] *= inv; by[h] *= inv; bz[h] *= inv;
    }
  }
  __syncthreads();  // xsf/yhf dead; ht overlays them

  // ---- Phase 2: h1 (bf16) transposed into ht[d][local node] ----
  if (act) {
    #pragma unroll
    for (int h = 0; h < 4; ++h) {
      int co = h * 16;
      #pragma unroll
      for (int c = 0; c < 16; ++c) {
        int d = co + c;
        float hd = fmaxf(bx[h] * w1s[512 + d] + by[h] * w1s[576 + d] +
                         bz[h] * w1s[640 + d] + w1s[704 + d], 0.f);
        ht[d * 208 + tid] = f2bf(hd);
      }
    }
  }
  __syncthreads();

  // ---- Phase 3: gat2_proj thread mapping over the 200 local nodes ----
  {
    const int c = tid & 31, ng = tid >> 5;
    const float* wq = g2;
    const float* wk = g2 + 2080;
    const float* wv = g2 + 4160;
    const float bq = g2[2048 + c], bk = g2[4128 + c], bv = g2[6208 + c];
    for (int base = 0; base < 200; base += 64) {
      const int nb = base + ng * 8;
      if (nb < 200) {
        float qa[8], ka[8], va[8];
        #pragma unroll
        for (int k = 0; k < 8; ++k) { qa[k] = bq; ka[k] = bk; va[k] = bv; }
        for (int d = 0; d < 64; ++d) {
          float wqv = wq[d * 32 + c], wkv = wk[d * 32 + c], wvv = wv[d * 32 + c];
          uint4 hv4 = *(const uint4*)(ht + d * 208 + nb);
          unsigned uu[4] = {hv4.x, hv4.y, hv4.z, hv4.w};
          #pragma unroll
          for (int m = 0; m < 4; ++m) {
            float h0 = bflo(uu[m]), h1v = bfhi(uu[m]);
            qa[2*m] += h0 * wqv;   qa[2*m+1] += h1v * wqv;
            ka[2*m] += h0 * wkv;   ka[2*m+1] += h1v * wkv;
            va[2*m] += h0 * wvv;   va[2*m+1] += h1v * wvv;
          }
        }
        #pragma unroll
        for (int k = 0; k < 8; ++k) {
          size_t gn = (size_t)g * NN + i0 + nb + k;
          q2b[gn * 32 + c] = f2bf(qa[k]);
          k2g[gn * 32 + c] = f2bf(ka[k]);
          v2g[gn * 32 + c] = f2bf(va[k]);
        }
      }
    }
  }
}

// ---------------------------------------------------------------------------
// GAT2 attention + residual + LN. grid (192, 2): 200 nodes per block; full
// K/V staged bf16 (uint2), 80B rows. spo written [b][n][s][32].
// ---------------------------------------------------------------------------
__global__ __launch_bounds__(256) void gat2_attn_k(
    const void* __restrict__ xraw, const unsigned short* __restrict__ probe,
    const unsigned short* __restrict__ q2b, const unsigned short* __restrict__ k2g,
    const unsigned short* __restrict__ v2g, const float* __restrict__ spw,
    const int* __restrict__ colp, const int* __restrict__ degp,
    float* __restrict__ spo) {
  __shared__ unsigned short k2s[NN * 40];
  __shared__ unsigned short v2s[NN * 40];
  __shared__ float gw[64];
  const int tid = threadIdx.x;
  const int g = blockIdx.x;
  bool isbf = detect_bf16(probe);
  if (tid < 64) gw[tid] = spw[tid];
  for (int e = tid; e < 3200; e += 256) {
    uint2 uk = ((const uint2*)k2g)[g * 3200 + e];
    uint2 uv = ((const uint2*)v2g)[g * 3200 + e];
    int n = e >> 3, c = (e & 7) * 2;
    *(uint2*)((unsigned*)k2s + n * 20 + c) = uk;
    *(uint2*)((unsigned*)v2s + n * 20 + c) = uv;
  }
  __syncthreads();
  const int b = g / 24, st = g % 24;
  const int i0 = blockIdx.y * 200;
  for (int i = i0 + tid; i < i0 + 200; i += 256) {
    const uint4* qp = (const uint4*)(q2b + ((size_t)g * NN + i) * 32);
    uint4 qw[4] = {qp[0], qp[1], qp[2], qp[3]};
    float q[32], o[32];
    #pragma unroll
    for (int t = 0; t < 4; ++t) {
      unsigned uu[4] = {qw[t].x, qw[t].y, qw[t].z, qw[t].w};
      #pragma unroll
      for (int m = 0; m < 4; ++m) {
        q[t * 8 + 2 * m] = bflo(uu[m]); q[t * 8 + 2 * m + 1] = bfhi(uu[m]);
      }
    }
    #pragma unroll
    for (int c = 0; c < 32; ++c) o[c] = 0.f;
    int dg = degp[i];
    const int* cols = colp + i * KMAX;
    float l = 0.f;
    for (int e = 0; e < dg; ++e) {
      int j = cols[e];
      const uint4* kr = (const uint4*)(k2s + j * 40);
      const uint4* vr = (const uint4*)(v2s + j * 40);
      float s = 0.f;
      #pragma unroll
      for (int t = 0; t < 4; ++t) {
        uint4 kk = kr[t];
        unsigned uu[4] = {kk.x, kk.y, kk.z, kk.w};
        #pragma unroll
        for (int m = 0; m < 4; ++m)
          s += q[t * 8 + 2 * m] * bflo(uu[m]) + q[t * 8 + 2 * m + 1] * bfhi(uu[m]);
      }
      float p = __expf(s * 0.17677669529663688f);
      l += p;
      #pragma unroll
      for (int t = 0; t < 4; ++t) {
        uint4 vv = vr[t];
        unsigned uu[4] = {vv.x, vv.y, vv.z, vv.w};
        #pragma unroll
        for (int m = 0; m < 4; ++m) {
          o[t * 8 + 2 * m]     += p * bflo(uu[m]);
          o[t * 8 + 2 * m + 1] += p * bfhi(uu[m]);
        }
      }
    }
    float inv = 1.f / l;
    float xr[3];
    #pragma unroll
    for (int a = 0; a < 3; ++a) {
      if (isbf) xr[a] = __bfloat162float(((const __hip_bfloat16*)xraw)[((size_t)g * NN + i) * 3 + a]);
      else      xr[a] = ((const float*)xraw)[((size_t)g * NN + i) * 3 + a];
    }
    float row[32];
    #pragma unroll
    for (int c = 0; c < 32; ++c) row[c] = o[c] * inv;
    row[0] += xr[0]; row[1] += xr[1]; row[2] += xr[2];
    float mean = 0.f;
    #pragma unroll
    for (int c = 0; c < 32; ++c) mean += row[c];
    mean *= (1.f / 32.f);
    float var = 0.f;
    #pragma unroll
    for (int c = 0; c < 32; ++c) { float dd = row[c] - mean; var += dd * dd; }
    var *= (1.f / 32.f);
    float rinv = 1.f / sqrtf(var + 1e-6f);
    float4* so4 = (float4*)(spo + (((size_t)b * NN + i) * 24 + st) * 32);
    #pragma unroll
    for (int k = 0; k < 8; ++k) {
      float4 v;
      v.x = gw[4 * k]     * (row[4 * k]     - mean) * rinv + gw[32 + 4 * k];
      v.y = gw[4 * k + 1] * (row[4 * k + 1] - mean) * rinv + gw[33 + 4 * k];
      v.z = gw[4 * k + 2] * (row[4 * k + 2] - mean) * rinv + gw[34 + 4 * k];
      v.w = gw[4 * k + 3] * (row[4 * k + 3] - mean) * rinv + gw[35 + 4 * k];
      so4[k] = v;
    }
  }
}

// ---------------------------------------------------------------------------
// Temporal transformer + fuse — R9 structure at 192 threads/block: wave a
// owns matrix a in QKV (1 weight array, 24 rows, 33% less per-thread work),
// FF1 3 shards of 8 rows, grid-stride constants 128->192. LDS unchanged
// (26.6 KB -> 6 blocks/CU -> 18 waves/CU cap vs 12 at 128 thr). All
// pair-shuffles remain intra-wave. VGPR budget unchanged (~68).
// LDS (dw): t_s 0 [24][32] | q_s 768 [24][65] | k_s 2328 | v_s 3888 |
//           aw 5448 [48][25] (x1s [24][33] aliases @5448 after att) -> 6648.
// ---------------------------------------------------------------------------
__global__ __launch_bounds__(192) void temporal_k(
    const float* __restrict__ sp, const float* __restrict__ tw,
    const unsigned short* __restrict__ probe, void* __restrict__ outp) {
  __shared__ float sm[6648];
  float* t_s = sm;             // [24][32]
  float* q_s = sm + 768;       // [24][65]
  float* k_s = sm + 2328;      // [24][65]
  float* v_s = sm + 3888;      // [24][65]
  float* aw  = sm + 5448;      // [48][25]
  float* x1s = sm + 5448;      // [24][33], aliases aw (aw dead by then)
  float* att = q_s;            // alias: q dead after scores
  float* f1s = k_s;            // alias: k dead after scores ([24][64] linear)
  float* tos = v_s;            // alias: v dead after att    ([24][33])
  const int tid = threadIdx.x;
  bool isbf = detect_bf16(probe);

  const float* twq = tw;            const float* tbq = tw + 2048;
  const float* twk = tw + 2112;     const float* tbk = tw + 4160;
  const float* twv = tw + 4224;     const float* tbv = tw + 6272;
  const float* two = tw + 6336;     const float* tbo = tw + 8384;
  const float* fw1 = tw + 8416;     const float* fb1 = tw + 10464;
  const float* fw2 = tw + 10528;    const float* fb2 = tw + 12576;
  const float* l1g = tw + 12608;    const float* l1b = tw + 12640;
  const float* l2g = tw + 12672;    const float* l2b = tw + 12704;
  const float* fng = tw + 12736;    const float* fnb = tw + 12768;
  const float* fdw = tw + 12800;    const float* fdb = tw + 12832;

  const float4* base4 = (const float4*)(sp + (size_t)blockIdx.x * 768);
  for (int e = tid; e < 192; e += 192) ((float4*)t_s)[e] = base4[e];
  __syncthreads();

  // QKV: wave a owns matrix a (0=q,1=k,2=v); lane owns column hk; 24 rows.
  {
    const int hk = tid & 63, a = tid >> 6;
    const float* W  = (a == 0) ? twq : (a == 1) ? twk : twv;
    const float* Bb = (a == 0) ? tbq : (a == 1) ? tbk : tbv;
    float* dst      = (a == 0) ? q_s : (a == 1) ? k_s : v_s;
    float w[32];
    #pragma unroll
    for (int c = 0; c < 32; ++c) w[c] = W[c * 64 + hk];
    float bias = Bb[hk];
    for (int s = 0; s < 24; ++s) {
      float acc = bias;
      const float* tr = t_s + s * 32;
      #pragma unroll
      for (int c = 0; c < 32; ++c) acc += tr[c] * w[c];
      dst[s * 65 + hk] = acc;
    }
  }
  __syncthreads();

  // scores + softmax: 96 lanes, 12 keys each, pair-combine via shfl_xor
  // (pairs (2k,2k+1) never cross a 64-lane wave boundary).
  if (tid < 96) {
    const int h = tid / 48, rem = tid % 48, qs = rem >> 1, half = rem & 1;
    const float* qr = q_s + qs * 65 + h * 32;
    float sc[12], l = 0.f;
    #pragma unroll
    for (int k = 0; k < 12; ++k) {
      const float* kr = k_s + (half * 12 + k) * 65 + h * 32;
      float s = 0.f;
      #pragma unroll
      for (int d = 0; d < 32; ++d) s += qr[d] * kr[d];
      sc[k] = __expf(s * 0.17677669529663688f);
      l += sc[k];
    }
    l += __shfl_xor(l, 1);
    float inv = 1.f / l;
    float* ar = aw + (h * 24 + qs) * 25 + half * 12;
    #pragma unroll
    for (int k = 0; k < 12; ++k) ar[k] = sc[k] * inv;
  }
  __syncthreads();

  // attention output (writes att = q_s alias; aw read, dead after this)
  for (int e = tid; e < 1536; e += 192) {
    int qs = e >> 6, hk = e & 63, h = hk >> 5;
    const float* ar = aw + (h * 24 + qs) * 25;
    float a = 0.f;
    #pragma unroll
    for (int ss = 0; ss < 24; ++ss) a += ar[ss] * v_s[ss * 65 + hk];
    att[qs * 65 + hk] = a;
  }
  __syncthreads();

  // output projection + residual (x1s overwrites dead aw region)
  for (int e = tid; e < 768; e += 192) {
    int s = e >> 5, c = e & 31;
    const float* ar = att + s * 65;
    float a = tbo[c];
    #pragma unroll 8
    for (int hk = 0; hk < 64; ++hk) a += ar[hk] * two[hk * 32 + c];
    x1s[s * 33 + c] = t_s[e] + a;
  }
  __syncthreads();
  if (tid < 24) {  // LN1
    float* r = x1s + tid * 33;
    float mean = 0.f;
    for (int c = 0; c < 32; ++c) mean += r[c];
    mean *= (1.f / 32.f);
    float var = 0.f;
    for (int c = 0; c < 32; ++c) { float d = r[c] - mean; var += d * d; }
    var *= (1.f / 32.f);
    float ri = 1.f / sqrtf(var + 1e-6f);
    for (int c = 0; c < 32; ++c) r[c] = l1g[c] * (r[c] - mean) * ri + l1b[c];
  }
  __syncthreads();

  // FF1 + exact gelu (writes f1s = k_s alias); 3 shards of 8 rows
  {
    const int j = tid & 63, sh = tid >> 6;
    float w[32];
    #pragma unroll
    for (int c = 0; c < 32; ++c) w[c] = fw1[c * 64 + j];
    float bias = fb1[j];
    for (int s = sh * 8; s < sh * 8 + 8; ++s) {
      float acc = bias;
      const float* xr = x1s + s * 33;
      #pragma unroll
      for (int c = 0; c < 32; ++c) acc += xr[c] * w[c];
      f1s[s * 64 + j] = 0.5f * acc * (1.f + erff(acc * 0.70710678118654752f));
    }
  }
  __syncthreads();

  // FF2 + residual (writes tos = v_s alias)
  for (int e = tid; e < 768; e += 192) {
    int s = e >> 5, c = e & 31;
    const float* fr = f1s + s * 64;
    float a = fb2[c];
    #pragma unroll 8
    for (int j = 0; j < 64; ++j) a += fr[j] * fw2[j * 32 + c];
    tos[s * 33 + c] = x1s[s * 33 + c] + a;
  }
  __syncthreads();
  if (tid < 24) {  // LN2
    float* r = tos + tid * 33;
    float mean = 0.f;
    for (int c = 0; c < 32; ++c) mean += r[c];
    mean *= (1.f / 32.f);
    float var = 0.f;
    for (int c = 0; c < 32; ++c) { float d = r[c] - mean; var += d * d; }
    var *= (1.f / 32.f);
    float ri = 1.f / sqrtf(var + 1e-6f);
    for (int c = 0; c < 32; ++c) r[c] = l2g[c] * (r[c] - mean) * ri + l2b[c];
  }
  __syncthreads();

  // fuse: wave 0 lanes 0..31, shfl LN + dense
  if (tid < 32) {
    const int c = tid;
    float ms = 0.f, mt = 0.f;
    #pragma unroll
    for (int s = 0; s < 24; ++s) { ms += t_s[s * 32 + c]; mt += tos[s * 33 + c]; }
    float red = (ms + mt) * (1.f / 24.f);
    float mean = rsum32(red) * (1.f / 32.f);
    float dv = red - mean;
    float var = rsum32(dv * dv) * (1.f / 32.f);
    float ri = 1.f / sqrtf(var + 1e-6f);
    float y = (fng[c] * dv * ri + fnb[c]) * fdw[c];
    float tot = rsum32(y);
    if (c == 0) {
      float acc = tot + fdb[0];
      if (isbf) ((__hip_bfloat16*)outp)[blockIdx.x] = __float2bfloat16(acc);
      else      ((float*)outp)[blockIdx.x] = acc;
    }
  }
}

// ---------------------------------------------------------------------------
extern "C" void kernel_launch(void* const* d_in, const int* in_sizes, int n_in,
                              void* d_out, int out_size, void* d_ws, size_t ws_size,
                              hipStream_t stream) {
  static const int wsizes[34] = {
      192, 64, 192, 64, 192, 64,
      2048, 32, 2048, 32, 2048, 32,
      32, 32,
      2048, 64, 2048, 64, 2048, 64, 2048, 32,
      2048, 64, 2048, 32,
      32, 32, 32, 32, 32, 32,
      32, 1};
  WTab wt;
  int off = 0;
  for (int i = 0; i < 34; ++i) { wt.p[i] = d_in[i + 2]; wt.off[i] = off; off += wsizes[i]; }
  wt.off[34] = off;  // 19905

  char* ws = (char*)d_ws;
  float* convw = (float*)ws;                               // 19905 f
  int*   colp  = (int*)(ws + 81920);                       // 400*64
  int*   degp  = (int*)(ws + 184320);                      // 400
  unsigned short* q2b = (unsigned short*)(ws + 196608);    // 4.92 MB
  unsigned short* k2g = (unsigned short*)(ws + 5242880);   // 4.92 MB
  unsigned short* v2g = (unsigned short*)(ws + 10289152);  // 4.92 MB
  float*          spo = (float*)(ws + 15335424);           // 9.83 MB -> ~25.2 MB

  const float* g1  = convw;
  const float* g2  = convw + 768;
  const float* spw = convw + 7008;
  const float* twp = convw + 7072;
  const unsigned short* probe = (const unsigned short*)d_in[0];

  hipLaunchKernelGGL(prep_k, dim3(140), dim3(256), 0, stream, wt, d_in[1], probe,
                     convw, colp, degp);
  hipLaunchKernelGGL(gat1proj_k, dim3(192, 2), dim3(256), 0, stream, d_in[0],
                     probe, g1, g2, (const int*)colp, (const int*)degp,
                     q2b, k2g, v2g);
  hipLaunchKernelGGL(gat2_attn_k, dim3(192, 2), dim3(256), 0, stream, d_in[0],
                     probe, (const unsigned short*)q2b, (const unsigned short*)k2g,
                     (const unsigned short*)v2g, spw, (const int*)colp,
                     (const int*)degp, spo);
  hipLaunchKernelGGL(temporal_k, dim3(3200), dim3(192), 0, stream,
                     (const float*)spo, twp, probe, d_out);
}